// Round 10
// baseline (495.371 us; speedup 1.0000x reference)
//
#include <hip/hip_runtime.h>

// Dilated conv2d as implicit GEMM, parity-ring edition, round 10:
// round-9 structure (proven 467 us, no spill), single change: MFMA shape
// 16x16x32 -> 32x32x16 (same A/B traffic, half the MFMA instructions,
// +15% rate per ubench). Wave tile stays 64co x 64pos: mi(2) x nj(2) pos
// tiles of 32 x K-halves c(2) = 8 MFMAs/tap, acc = 2x2 floatx16 = 64 regs.
// A lane map: m=l&31 (co), k=8*(l>>5)+j (cin-within-half); B: n=l&31 (pos).
// C/D (m74/m101): col=lane&31 -> pos, row=(reg&3)+8*(reg>>2)+4*(lane>>5) -> co.

#define CIN 32
#define HH 512
#define WW 512
#define COUT 64
#define OH 508
#define OW 496
#define KH 5
#define KW 9

#define WTILE 128
#define SW 152              // staged width: 128 + 24 halo (origin iw = w0-4)
#define OCT_STRIDE 1224     // SW*8 + 8 elts = 2448B (16B-aligned, banks spread)
#define SLOT_STRIDE 4896    // 4 * OCT_STRIDE elts = 9792B per row-slab
#define NSLOT 8             // ring: 6 active + 2 prefetch (78336 B total)
#define NIT 304             // staging items per row: (SW/4)*8
#define STEPS 16            // 2 oh rows per step -> 32 same-parity oh per block

typedef short short8 __attribute__((ext_vector_type(8)));
typedef float floatx16 __attribute__((ext_vector_type(16)));
typedef unsigned short u16;
typedef unsigned int u32;

__device__ __forceinline__ u16 f2bf(float f) {  // RNE f32->bf16
    u32 u = __float_as_uint(f);
    return (u16)((u + 0x7fffu + ((u >> 16) & 1u)) >> 16);
}

__global__ void repack_w_k(const float* __restrict__ w, u16* __restrict__ wr) {
    int idx = blockIdx.x * 256 + threadIdx.x;
    if (idx >= KH * KW * COUT * CIN) return;
    int tap = idx / (COUT * CIN);
    int rem = idx - tap * (COUT * CIN);
    int co = rem / CIN;
    int ci = rem - co * CIN;
    int r  = tap / KW;
    int kw = tap - r * KW;
    wr[idx] = f2bf(w[((co * CIN + ci) * KH + r) * KW + kw]);
}

__global__ __launch_bounds__(256, 2)
void conv_ring(const float* __restrict__ x, const u16* __restrict__ wrep,
               float* __restrict__ out) {
    __shared__ u16 s[NSLOT * SLOT_STRIDE];  // 78336 B -> 2 blocks/CU

    const int bx     = blockIdx.x;          // 0..7: wt(2b) | parity(1b)
    const int wt     = bx & 3;
    const int parity = bx >> 2;
    const int chunk  = blockIdx.y;          // 0..7
    const int b      = blockIdx.z;          // 0..7
    const int w0     = wt * WTILE;
    const int oh0    = parity + 64 * chunk;
    const int ihbase = oh0 - 2;
    const int iwbase = w0 - 4;

    const int tid  = threadIdx.x;
    const int lane = tid & 63;
    const int wave = tid >> 6;
    const int wp   = wave & 1;   // pos half (64)
    const int wo   = wave >> 1;  // which of the 2 oh rows this step
    const int l31  = lane & 31;
    const int lh   = lane >> 5;  // 0/1: K-half sub-group

    const size_t cstr = (size_t)HH * WW;    // x channel stride
    const float* xb = x + (size_t)b * CIN * cstr;

    // ---------------- prologue: stage rows j = 0..5 ----------------
    for (int it = tid; it < 6 * NIT; it += 256) {
        int j   = it / NIT;
        int rem = it - j * NIT;
        int w4  = rem >> 3;
        int q   = rem & 7;      // cin quad: cin = 4q..4q+3
        int ih  = ihbase + 2 * j;
        int iw0 = iwbase + 4 * w4;
        float4 m0 = {0,0,0,0}, m1 = {0,0,0,0}, m2 = {0,0,0,0}, m3 = {0,0,0,0};
        if ((unsigned)ih < HH && (unsigned)iw0 < WW) {
            const float* p = xb + (size_t)(4 * q) * cstr + (size_t)ih * WW + iw0;
            m0 = *(const float4*)(p);
            m1 = *(const float4*)(p + cstr);
            m2 = *(const float4*)(p + 2 * cstr);
            m3 = *(const float4*)(p + 3 * cstr);
        }
        u16* dst = s + (j & 7) * SLOT_STRIDE + (q >> 1) * OCT_STRIDE + (q & 1) * 4;
        const float* f0 = (const float*)&m0; const float* f1 = (const float*)&m1;
        const float* f2 = (const float*)&m2; const float* f3 = (const float*)&m3;
        #pragma unroll
        for (int jj = 0; jj < 4; ++jj) {
            u32 lo = (u32)f2bf(f0[jj]) | ((u32)f2bf(f1[jj]) << 16);
            u32 hi = (u32)f2bf(f2[jj]) | ((u32)f2bf(f3[jj]) << 16);
            *(uint2*)(dst + (4 * w4 + jj) * 8) = make_uint2(lo, hi);
        }
    }
    __syncthreads();

    // A: lane l -> co = l&31 (within 32-tile), cin = c*16 + 8*(l>>5) + j
    const u16* abase0 = wrep + l31 * CIN + 8 * lh;
    // B: lane l -> wi = posb + nj*32 + (l&31), oct = 2c + (l>>5)
    const int  bfixed = lh * OCT_STRIDE + (64 * wp + l31) * 8;

    floatx16 acc[2][2];

    #pragma unroll 1
    for (int st = 0; st < STEPS; ++st) {
        #pragma unroll
        for (int mi = 0; mi < 2; ++mi)
            #pragma unroll
            for (int nj = 0; nj < 2; ++nj)
                acc[mi][nj] = (floatx16)(0.f);

        // ---- A. issue prefetch loads for rows 2st+6, 2st+7 (regs) ----
        const bool doPref = (st < STEPS - 1);
        float4 pv[3][4];
        #pragma unroll
        for (int k = 0; k < 3; ++k) {
            #pragma unroll
            for (int c = 0; c < 4; ++c) pv[k][c] = (float4){0,0,0,0};
            int it = tid + 256 * k;
            if (doPref && it < 2 * NIT) {
                int second = (it >= NIT);
                int rem = it - (second ? NIT : 0);
                int j   = 2 * st + 6 + second;
                int w4  = rem >> 3;
                int q   = rem & 7;
                int ih  = ihbase + 2 * j;
                int iw0 = iwbase + 4 * w4;
                if ((unsigned)ih < HH && (unsigned)iw0 < WW) {
                    const float* p = xb + (size_t)(4 * q) * cstr + (size_t)ih * WW + iw0;
                    pv[k][0] = *(const float4*)(p);
                    pv[k][1] = *(const float4*)(p + cstr);
                    pv[k][2] = *(const float4*)(p + 2 * cstr);
                    pv[k][3] = *(const float4*)(p + 3 * cstr);
                }
            }
        }

        // ---- B. 45 taps: r serial, kw fully unrolled, 8x 32x32x16 per tap ----
        const int js = 2 * st;
        #pragma unroll 1
        for (int r = 0; r < KH; ++r) {
            const u16* bb = s + ((js + wo + r) & 7) * SLOT_STRIDE + bfixed;
            const u16* ab = abase0 + (size_t)(r * KW) * (COUT * CIN);
            #pragma unroll
            for (int kw = 0; kw < KW; ++kw) {
                short8 af[2][2], bf_[2][2];
                #pragma unroll
                for (int mi = 0; mi < 2; ++mi)
                    #pragma unroll
                    for (int c = 0; c < 2; ++c)
                        af[mi][c] = *(const short8*)(ab + (kw * COUT + mi * 32) * CIN + c * 16);
                #pragma unroll
                for (int nj = 0; nj < 2; ++nj)
                    #pragma unroll
                    for (int c = 0; c < 2; ++c)
                        bf_[nj][c] = *(const short8*)(bb + (32 * nj + 3 * kw) * 8 + c * 2 * OCT_STRIDE);
                __builtin_amdgcn_s_setprio(1);
                #pragma unroll
                for (int c = 0; c < 2; ++c)
                    #pragma unroll
                    for (int mi = 0; mi < 2; ++mi)
                        #pragma unroll
                        for (int nj = 0; nj < 2; ++nj)
                            acc[mi][nj] = __builtin_amdgcn_mfma_f32_32x32x16_bf16(
                                af[mi][c], bf_[nj][c], acc[mi][nj], 0, 0, 0);
                __builtin_amdgcn_s_setprio(0);
            }
        }

        // ---- C. convert + ds_write the prefetched rows into ring ----
        if (doPref) {
            #pragma unroll
            for (int k = 0; k < 3; ++k) {
                int it = tid + 256 * k;
                if (it < 2 * NIT) {
                    int second = (it >= NIT);
                    int rem = it - (second ? NIT : 0);
                    int j   = 2 * st + 6 + second;
                    int w4  = rem >> 3;
                    int q   = rem & 7;
                    u16* dst = s + (j & 7) * SLOT_STRIDE + (q >> 1) * OCT_STRIDE + (q & 1) * 4;
                    const float* f0 = (const float*)&pv[k][0];
                    const float* f1 = (const float*)&pv[k][1];
                    const float* f2 = (const float*)&pv[k][2];
                    const float* f3 = (const float*)&pv[k][3];
                    #pragma unroll
                    for (int jj = 0; jj < 4; ++jj) {
                        u32 lo = (u32)f2bf(f0[jj]) | ((u32)f2bf(f1[jj]) << 16);
                        u32 hi = (u32)f2bf(f2[jj]) | ((u32)f2bf(f3[jj]) << 16);
                        *(uint2*)(dst + (4 * w4 + jj) * 8) = make_uint2(lo, hi);
                    }
                }
            }
        }
        __syncthreads();

        // ---- D. store: col=lane&31 -> pos, row=(reg&3)+8*(reg>>2)+4*lh -> co ----
        const int oh = oh0 + 4 * st + 2 * wo;
        if (oh < OH) {
            #pragma unroll
            for (int nj = 0; nj < 2; ++nj) {
                const int pos = w0 + 64 * wp + 32 * nj + l31;
                if (pos < OW) {  // per-lane guard: 496 is not a multiple of 32
                    #pragma unroll
                    for (int mi = 0; mi < 2; ++mi) {
                        #pragma unroll
                        for (int reg = 0; reg < 16; ++reg) {
                            const int co = mi * 32 + (reg & 3) + 8 * (reg >> 2) + 4 * lh;
                            out[(((size_t)(b * COUT + co) * OH + oh) * OW) + pos] =
                                acc[mi][nj][reg];
                        }
                    }
                }
            }
        }
    }
}

extern "C" void kernel_launch(void* const* d_in, const int* in_sizes, int n_in,
                              void* d_out, int out_size, void* d_ws, size_t ws_size,
                              hipStream_t stream) {
    const float* x = (const float*)d_in[0];
    const float* w = (const float*)d_in[1];
    float* out = (float*)d_out;
    u16* wrep = (u16*)d_ws;  // 45*64*32*2 = 184320 B

    repack_w_k<<<(KH * KW * COUT * CIN + 255) / 256, 256, 0, stream>>>(w, wrep);

    dim3 grid(8 /* wt(4) x parity(2) */, 8 /* chunks */, 8 /* batch */);
    conv_ring<<<grid, dim3(256), 0, stream>>>(x, wrep, out);
}